// Round 7
// baseline (29.735 us; speedup 1.0000x reference)
//
#include <hip/hip_runtime.h>
#include <math.h>

// RandISH, per-b compute + LDS-transpose coalesced stores.
//   out[b, 2n+0] = Al(deg_n, r_b) * y0_norm[n] * P_l(ct)
//   out[b, 2n+1] = Al * cscale[n] * (-1)^deg * Re[(rx + i*ry)^deg]
// rv = vec[b] @ M[n]; rotation preserves |vec|=1 -> no normalization.
//
// Layout: 64-thread blocks (1 wave), lane = direction b. All per-n data
// (deg, mats, coeffs, scales) is WAVE-UNIFORM -> SGPRs + uniform branches;
// the Re[z^d] recurrence runs only deg-1 real iterations (54% of degs are 1).
// Round-4 counters proved this compute model costs only ~8us chip-wide;
// its killer was scattered 16B stores (WRITE_SIZE 166MB, 2.5x amplified).
// Fix: stage each lane's 64 outputs in an LDS row (stride 65 dwords, odd ->
// bank-conflict-free b32 writes), then stream the 16KB wave tile to HBM as
// 16 x 1KB coalesced nontemporal dwordx4 stores (full lines, no RMW).
//
// Re[z^d]: R_k = 2x R_{k-1} - (x^2+y^2) R_{k-2},  R_0=1, R_1=x.
// Al = exp2(-0.5*log2e*d(d+1)*(r+eps))   (0.5/(1/(r+e)+e) ~= 0.5(r+e), 1e-8 rel).

#define NBASIS 32
#define PLEN 10
#define EPSV 1e-8f
#define LOG2E 1.44269504088896340736f
#define ROWD 65   // LDS row stride in dwords (odd -> all 32 banks covered)

typedef float f32x4 __attribute__((ext_vector_type(4)));

__global__ __launch_bounds__(64) void randish_kernel(
    const float* __restrict__ vec,        // (B,3)
    const float* __restrict__ rough,      // (B,)
    const float* __restrict__ mats,       // (32,3,3)
    const float* __restrict__ coeffs,     // (32,10) increasing power
    const float* __restrict__ cscale,     // (32,)
    const float* __restrict__ y0n,        // (32,)
    const int*   __restrict__ degs,       // (32,)
    float* __restrict__ out,              // (B,64)
    int B)
{
    __shared__ float lds[64 * ROWD];

    const int lane = threadIdx.x;          // 0..63
    const int b0   = blockIdx.x * 64;
    const int b    = b0 + lane;            // B % 64 == 0, always in range

    const float v0 = vec[b * 3 + 0];
    const float v1 = vec[b * 3 + 1];
    const float v2 = vec[b * 3 + 2];
    // Al = exp2( (d*(d+1)) * tec ),  tec = -0.5*log2e*(r+eps)  (hoisted, 1 mul/n)
    const float tec = (rough[b] + EPSV) * (-0.5f * LOG2E);

    float* row = &lds[lane * ROWD];

#pragma unroll
    for (int n = 0; n < NBASIS; ++n) {
        const int d   = degs[n];           // wave-uniform -> SGPR
        const int par = d & 1;             // uniform

        // rotate (|rv| == 1); mats entries are uniform scalar operands
        const float xh = fmaf(v0, mats[n*9+0], fmaf(v1, mats[n*9+3], v2 * mats[n*9+6]));
        const float yh = fmaf(v0, mats[n*9+1], fmaf(v1, mats[n*9+4], v2 * mats[n*9+7]));
        const float ct = fmaf(v0, mats[n*9+2], fmaf(v1, mats[n*9+5], v2 * mats[n*9+8]));

        // Legendre: P_l(ct) = ct^par * H(ct^2), parity-compressed, zero-padded
        const float ct2 = ct * ct;
        float v = coeffs[n*PLEN + par + 8];
        v = fmaf(v, ct2, coeffs[n*PLEN + par + 6]);
        v = fmaf(v, ct2, coeffs[n*PLEN + par + 4]);
        v = fmaf(v, ct2, coeffs[n*PLEN + par + 2]);
        v = fmaf(v, ct2, coeffs[n*PLEN + par + 0]);
        if (par) v *= ct;                  // uniform branch

        // Re[(xh+i*yh)^d]: uniform trip count (deg=1 -> zero iterations)
        float R = xh;
        if (d > 1) {
            const float ss  = fmaf(yh, yh, xh * xh);
            const float m2x = xh + xh;
            float Rm2 = 1.0f, Rm1 = xh;
            for (int k = 2; k <= d; ++k) {
                const float Rk = fmaf(m2x, Rm1, -(ss * Rm2));
                Rm2 = Rm1;
                Rm1 = Rk;
            }
            R = Rm1;
        }
        float cs = cscale[n];
        if (par) cs = -cs;                 // fold (-1)^deg, uniform

        const float al = __builtin_amdgcn_exp2f((float)(d * (d + 1)) * tec);

        // conflict-free LDS writes: bank = (65*lane + 2n + j) % 32, odd stride
        row[2 * n + 0] = al * (y0n[n] * v);
        row[2 * n + 1] = al * (cs * R);
    }

    __syncthreads();

    // store phase: wave tile = 64 b x 64 floats = 16 KB contiguous in out
    f32x4* outp = reinterpret_cast<f32x4*>(out + (size_t)b0 * 64);
#pragma unroll
    for (int i = 0; i < 16; ++i) {
        const int c   = i * 64 + lane;     // dwordx4 chunk index in tile
        const int r   = c >> 4;            // source LDS row
        const int col = (c & 15) * 4;      // dword column within row
        const float* src = &lds[r * ROWD + col];
        f32x4 o = { src[0], src[1], src[2], src[3] };
        __builtin_nontemporal_store(o, outp + c);   // 1 KB/wave, full lines
    }
}

extern "C" void kernel_launch(void* const* d_in, const int* in_sizes, int n_in,
                              void* d_out, int out_size, void* d_ws, size_t ws_size,
                              hipStream_t stream) {
    const float* vec    = (const float*)d_in[0];
    const float* rough  = (const float*)d_in[1];
    const float* mats   = (const float*)d_in[2];
    const float* coeffs = (const float*)d_in[3];
    const float* cscale = (const float*)d_in[4];
    const float* y0n    = (const float*)d_in[5];
    const int*   degs   = (const int*)d_in[6];
    float* out = (float*)d_out;

    const int B = in_sizes[1];             // roughness element count (262144)
    const int block = 64;                  // one wave per block
    const int grid = (B + block - 1) / block;

    randish_kernel<<<grid, block, 0, stream>>>(vec, rough, mats, coeffs, cscale,
                                               y0n, degs, out, B);
}

// Round 8
// 28.235 us; speedup vs baseline: 1.0531x; 1.0531x over previous
//
#include <hip/hip_runtime.h>
#include <math.h>

// RandISH, pair mapping + packed dual-FP32 + 4-deep software pipeline:
//   out[b, 2n+0] = Al(deg_n, r_b) * y0_norm[n] * P_l(ct)
//   out[b, 2n+1] = Al * cscale[n] * (-1)^deg * Re[(rx + i*ry)^deg]
// rv = vec[b] @ M[n]; rotation preserves |vec|=1 -> no normalization.
// Two bases (n0,n0+1) live in the lanes of f32x2 (v_pk_* dual-FP32).
// Each thread owns EXACTLY 4 pairs (compile-time trip count): all 16 input
// loads issue first (independent, one vmcnt window), then 4 independent
// unrolled compute streams (4x ILP on the dependent ALU chain), then 4
// plain f32x4 stores (67MB output fits L3; let L2 write-combine).
// Re[z^d]: R_k = 2x R_{k-1} - (x^2+y^2) R_{k-2}; all 8 steps computed
// (|R_k|<=1), result picked by mask-FMA with cscale*(-1)^deg folded in.
// Al = exp2(-0.5*log2e*d(d+1)*(r+eps)).

#define NBASIS 32
#define PLEN 10
#define EPSV 1e-8f
#define LOG2E 1.44269504088896340736f
#define NITER 4

typedef float f32x2 __attribute__((ext_vector_type(2)));
typedef float f32x4 __attribute__((ext_vector_type(4)));

static __device__ __forceinline__ f32x2 fma2(f32x2 a, f32x2 b, f32x2 c) {
    return __builtin_elementwise_fma(a, b, c);
}

__global__ __launch_bounds__(256) void randish_kernel(
    const float* __restrict__ vec,        // (B,3)
    const float* __restrict__ rough,      // (B,)
    const float* __restrict__ mats,       // (32,3,3)
    const float* __restrict__ coeffs,     // (32,10) increasing power
    const float* __restrict__ cscale,     // (32,)
    const float* __restrict__ y0n,        // (32,)
    const int*   __restrict__ degs,       // (32,)
    float* __restrict__ out,              // (B,64)
    int npairs)                           // B*16
{
    const int tid = blockIdx.x * blockDim.x + threadIdx.x;
    const int stride = gridDim.x * blockDim.x;   // multiple of 16 -> n0 invariant
    const int n0 = (2 * tid) & 31;               // slots are bases n0, n0+1

    // ---- per-slot constants, packed slot0/slot1 ----
    f32x2 m[9], h[5], msel[9], maskp, negc2;
    {
#pragma unroll
        for (int s = 0; s < 2; ++s) {
            const int n = n0 + s;
            const int d = degs[n];
            const int pr = d & 1;
            float c = cscale[n];
            if (pr) c = -c;                      // fold (-1)^deg
            const float yn = y0n[n];             // fold y0_norm into Horner coeffs
#pragma unroll
            for (int k = 0; k < 5; ++k) {
                const int idx = pr + 2 * k;      // parity-compressed Legendre
                h[k][s] = (idx < PLEN) ? coeffs[n * PLEN + idx] * yn : 0.0f;
            }
#pragma unroll
            for (int j = 0; j < 9; ++j) m[j][s] = mats[n * 9 + j];
            maskp[s] = (float)pr;
            negc2[s] = -0.5f * (float)(d * (d + 1)) * LOG2E;
#pragma unroll
            for (int k = 1; k <= 9; ++k)
                msel[k - 1][s] = (d == k) ? c : 0.0f;   // cscale folded in
        }
    }
    const f32x2 one2 = {1.0f, 1.0f};

    // ---- phase 1: issue ALL input loads (independent, fill the MEM pipe) ----
    float V0[NITER], V1[NITER], V2[NITER], TE[NITER];
    int   P[NITER];
    bool  OK[NITER];
#pragma unroll
    for (int i = 0; i < NITER; ++i) {
        const int p = tid + i * stride;
        P[i]  = p;
        OK[i] = (p < npairs);
        const int b = (OK[i] ? p : tid) >> 4;
        V0[i] = vec[b * 3 + 0];
        V1[i] = vec[b * 3 + 1];
        V2[i] = vec[b * 3 + 2];
        TE[i] = rough[b];
    }

    // ---- phase 2: 4 independent compute streams + stores ----
#pragma unroll
    for (int i = 0; i < NITER; ++i) {
        const f32x2 Va = {V0[i], V0[i]};
        const f32x2 Vb = {V1[i], V1[i]};
        const f32x2 Vc = {V2[i], V2[i]};
        const float te = TE[i] + EPSV;
        const f32x2 te2 = {te, te};

        // rotate (|rv| == 1)
        const f32x2 xh = fma2(Va, m[0], fma2(Vb, m[3], Vc * m[6]));
        const f32x2 yh = fma2(Va, m[1], fma2(Vb, m[4], Vc * m[7]));
        const f32x2 ct = fma2(Va, m[2], fma2(Vb, m[5], Vc * m[8]));

        // Legendre (y0_norm folded): y0 = ct^par * H(ct^2)
        const f32x2 ct2 = ct * ct;
        f32x2 v = h[4];
        v = fma2(v, ct2, h[3]);
        v = fma2(v, ct2, h[2]);
        v = fma2(v, ct2, h[1]);
        v = fma2(v, ct2, h[0]);
        const f32x2 ctp = fma2(maskp, ct - one2, one2);  // par ? ct : 1
        v = v * ctp;

        // cs * Re[(xh+i*yh)^deg] via recurrence + mask-FMA select
        const f32x2 ss  = fma2(yh, yh, xh * xh);
        const f32x2 m2x = xh + xh;
        f32x2 Rm2 = one2;
        f32x2 Rm1 = xh;
        f32x2 res = msel[0] * xh;                 // k = 1
#pragma unroll
        for (int k = 2; k <= 9; ++k) {
            const f32x2 Rk = fma2(m2x, Rm1, -(ss * Rm2));
            res = fma2(msel[k - 1], Rk, res);
            Rm2 = Rm1;
            Rm1 = Rk;
        }

        // Al = exp2(negc * (r+eps)) per slot
        const f32x2 e = negc2 * te2;
        const float al0 = __builtin_amdgcn_exp2f(e[0]);
        const float al1 = __builtin_amdgcn_exp2f(e[1]);

        f32x4 o;
        o[0] = al0 * v[0];
        o[1] = al0 * res[0];
        o[2] = al1 * v[1];
        o[3] = al1 * res[1];
        if (OK[i])
            reinterpret_cast<f32x4*>(out)[P[i]] = o;   // plain store: L2/L3 absorb
    }
}

extern "C" void kernel_launch(void* const* d_in, const int* in_sizes, int n_in,
                              void* d_out, int out_size, void* d_ws, size_t ws_size,
                              hipStream_t stream) {
    const float* vec    = (const float*)d_in[0];
    const float* rough  = (const float*)d_in[1];
    const float* mats   = (const float*)d_in[2];
    const float* coeffs = (const float*)d_in[3];
    const float* cscale = (const float*)d_in[4];
    const float* y0n    = (const float*)d_in[5];
    const int*   degs   = (const int*)d_in[6];
    float* out = (float*)d_out;

    const int B = in_sizes[1];              // roughness element count
    const int npairs = B * (NBASIS / 2);    // one thread per 2 consecutive outputs

    const int block = 256;
    const int grid = (npairs + block * NITER - 1) / (block * NITER);  // 4 pairs/thread

    randish_kernel<<<grid, block, 0, stream>>>(vec, rough, mats, coeffs, cscale,
                                               y0n, degs, out, npairs);
}